// Round 4
// baseline (231.672 us; speedup 1.0000x reference)
//
#include <hip/hip_runtime.h>
#include <hip/hip_bf16.h>

typedef __bf16 bf16_t;
typedef __bf16 bf16x4 __attribute__((ext_vector_type(4)));
typedef __bf16 bf16x8 __attribute__((ext_vector_type(8)));
typedef float floatx4 __attribute__((ext_vector_type(4)));

#define SEQ    8192
#define DM     1024
#define NHEADS 16
#define HDIM   64

// async global->LDS, 16B per lane; LDS dest is wave-uniform base + lane*16
__device__ __forceinline__ void async_ld16(bf16_t* lds, const bf16_t* g) {
  __builtin_amdgcn_global_load_lds(
      (__attribute__((address_space(1))) void*)g,
      (__attribute__((address_space(3))) void*)lds, 16, 0, 0);
}

// one launch converts x (8192 blocks) + 4 weight matrices (1024 blocks each)
__global__ __launch_bounds__(256)
void cvt_all(const float* __restrict__ x,  const float* __restrict__ qw,
             const float* __restrict__ kw, const float* __restrict__ vw,
             const float* __restrict__ ow,
             bf16_t* __restrict__ Xb,  bf16_t* __restrict__ QWb,
             bf16_t* __restrict__ KWb, bf16_t* __restrict__ VWb,
             bf16_t* __restrict__ OWb) {
  const int b = blockIdx.x;
  const float* in; bf16_t* out; int g;
  if (b < 8192) { in = x; out = Xb; g = b; }
  else {
    const int w  = (b - 8192) >> 10;
    const int wb = (b - 8192) & 1023;
    switch (w) {
      case 0:  in = qw; out = QWb; break;
      case 1:  in = kw; out = KWb; break;
      case 2:  in = vw; out = VWb; break;
      default: in = ow; out = OWb; break;
    }
    g = wb;
  }
  const int idx = (g * 256 + threadIdx.x) * 4;
  float4 v = *(const float4*)(in + idx);
  bf16x4 o = { (bf16_t)v.x, (bf16_t)v.y, (bf16_t)v.z, (bf16_t)v.w };
  *(bf16x4*)(out + idx) = o;
}

// Fused QKV projection: block computes a 128(M)x64(N) tile of Q, K, AND V,
// staging the shared A-tile once per K-step. Per wave per K-step:
// 24 MFMA (3 matrices x 4 row-tiles x 2 col-tiles) vs 16 in the unfused kernel,
// with 5 staging loads (2 A + 3 B) vs 4 -> 1.5x MFMA work per barrier-pair.
__global__ __launch_bounds__(256)
void gemm_qkv_fused(const bf16_t* __restrict__ A,
                    const bf16_t* __restrict__ Bq, const bf16_t* __restrict__ Bk,
                    const bf16_t* __restrict__ Bv,
                    bf16_t* __restrict__ Cq, bf16_t* __restrict__ Ck,
                    bf16_t* __restrict__ Cv)
{
  constexpr int Kdim = DM;
  __shared__ __attribute__((aligned(16))) bf16_t sA[128 * 32];
  __shared__ __attribute__((aligned(16))) bf16_t sB[3][64 * 32];

  const int tid  = threadIdx.x;
  const int wave = tid >> 6;
  const int lane = tid & 63;
  const int quad = lane >> 4;
  const int r16  = lane & 15;
  const int wr   = (wave >> 1) * 64;   // wave row offset in the 128-row tile
  const int wc   = (wave & 1) * 32;    // wave col offset in the 64-col tile

  // A staging: wave stages rows [wave*32, wave*32+32); lane L -> row L/4, k-chunk (L%4)*8
  const size_t arow = (size_t)blockIdx.x * 128 + wave * 32 + (lane >> 2);
  const bf16_t* Ag = A + arow * Kdim + (lane & 3) * 8;
  // B staging: per matrix, wave stages rows [wave*16, wave*16+16)
  const size_t brow = (size_t)blockIdx.y * 64 + wave * 16 + (lane >> 2);
  const bf16_t* Bqg = Bq + brow * Kdim + (lane & 3) * 8;
  const bf16_t* Bkg = Bk + brow * Kdim + (lane & 3) * 8;
  const bf16_t* Bvg = Bv + brow * Kdim + (lane & 3) * 8;
  bf16_t* sAw  = sA    + wave * 32 * 32;
  bf16_t* sB0w = sB[0] + wave * 16 * 32;
  bf16_t* sB1w = sB[1] + wave * 16 * 32;
  bf16_t* sB2w = sB[2] + wave * 16 * 32;

  floatx4 acc[3][4][2];
  #pragma unroll
  for (int t = 0; t < 3; ++t)
    #pragma unroll
    for (int i = 0; i < 4; ++i)
      #pragma unroll
      for (int j = 0; j < 2; ++j)
        acc[t][i][j] = (floatx4)(0.0f);

  for (int ko = 0; ko < Kdim; ko += 32) {
    async_ld16(sAw,           Ag + ko);
    async_ld16(sAw + 16 * 32, Ag + 16 * Kdim + ko);
    async_ld16(sB0w, Bqg + ko);
    async_ld16(sB1w, Bkg + ko);
    async_ld16(sB2w, Bvg + ko);
    __syncthreads();   // drains vmcnt, then barrier

    bf16x8 af[4];
    #pragma unroll
    for (int mi = 0; mi < 4; ++mi)
      af[mi] = *(const bf16x8*)&sA[(wr + mi * 16 + r16) * 32 + quad * 8];
    bf16x8 bfr[3][2];
    #pragma unroll
    for (int t = 0; t < 3; ++t)
      #pragma unroll
      for (int ni = 0; ni < 2; ++ni)
        bfr[t][ni] = *(const bf16x8*)&sB[t][(wc + ni * 16 + r16) * 32 + quad * 8];

    #pragma unroll
    for (int t = 0; t < 3; ++t)
      #pragma unroll
      for (int mi = 0; mi < 4; ++mi)
        #pragma unroll
        for (int ni = 0; ni < 2; ++ni)
          acc[t][mi][ni] = __builtin_amdgcn_mfma_f32_16x16x32_bf16(af[mi], bfr[t][ni], acc[t][mi][ni], 0, 0, 0);

    __syncthreads();   // protect LDS before next stage overwrites
  }

  // C/D layout: col = lane&15, row = (lane>>4)*4 + reg  [measured m89/m91]
  const int crow0 = blockIdx.x * 128 + wr + quad * 4;
  const int ccol0 = blockIdx.y * 64 + wc + r16;
  #pragma unroll
  for (int t = 0; t < 3; ++t) {
    bf16_t* C = (t == 0) ? Cq : (t == 1) ? Ck : Cv;
    #pragma unroll
    for (int mi = 0; mi < 4; ++mi)
      #pragma unroll
      for (int ni = 0; ni < 2; ++ni)
        #pragma unroll
        for (int r = 0; r < 4; ++r)
          C[(size_t)(crow0 + mi * 16 + r) * DM + (ccol0 + ni * 16)] = (bf16_t)acc[t][mi][ni][r];
  }
}

// Output projection: C[m][n] = sum_k A[m][k]*B[n][k], f32 out.
// 128x128 tile, BK=32, 4 waves (2x2 of 64x64), 16 MFMA 16x16x32 per K-step.
__global__ __launch_bounds__(256)
void gemm_out(const bf16_t* __restrict__ A, const bf16_t* __restrict__ B,
              float* __restrict__ C)
{
  constexpr int Kdim = DM;
  __shared__ __attribute__((aligned(16))) bf16_t sA[128 * 32];
  __shared__ __attribute__((aligned(16))) bf16_t sB[128 * 32];

  const int tid  = threadIdx.x;
  const int wave = tid >> 6;
  const int lane = tid & 63;
  const int quad = lane >> 4;
  const int r16  = lane & 15;
  const int wr   = (wave >> 1) * 64;
  const int wc   = (wave & 1) * 64;

  const size_t arow0 = (size_t)blockIdx.x * 128 + wave * 32 + (lane >> 2);
  const size_t brow0 = (size_t)blockIdx.y * 128 + wave * 32 + (lane >> 2);
  const bf16_t* Ag = A + arow0 * Kdim + (lane & 3) * 8;
  const bf16_t* Bg = B + brow0 * Kdim + (lane & 3) * 8;
  bf16_t* sAw = sA + wave * 32 * 32;
  bf16_t* sBw = sB + wave * 32 * 32;

  floatx4 acc[4][4];
  #pragma unroll
  for (int i = 0; i < 4; ++i)
    #pragma unroll
    for (int j = 0; j < 4; ++j)
      acc[i][j] = (floatx4)(0.0f);

  for (int ko = 0; ko < Kdim; ko += 32) {
    async_ld16(sAw,           Ag + ko);
    async_ld16(sAw + 16 * 32, Ag + 16 * Kdim + ko);
    async_ld16(sBw,           Bg + ko);
    async_ld16(sBw + 16 * 32, Bg + 16 * Kdim + ko);
    __syncthreads();

    bf16x8 af[4], bfr[4];
    #pragma unroll
    for (int mi = 0; mi < 4; ++mi)
      af[mi] = *(const bf16x8*)&sA[(wr + mi * 16 + r16) * 32 + quad * 8];
    #pragma unroll
    for (int ni = 0; ni < 4; ++ni)
      bfr[ni] = *(const bf16x8*)&sB[(wc + ni * 16 + r16) * 32 + quad * 8];

    #pragma unroll
    for (int mi = 0; mi < 4; ++mi)
      #pragma unroll
      for (int ni = 0; ni < 4; ++ni)
        acc[mi][ni] = __builtin_amdgcn_mfma_f32_16x16x32_bf16(af[mi], bfr[ni], acc[mi][ni], 0, 0, 0);

    __syncthreads();
  }

  const int crow0 = blockIdx.x * 128 + wr + quad * 4;
  const int ccol0 = blockIdx.y * 128 + wc + r16;
  #pragma unroll
  for (int mi = 0; mi < 4; ++mi)
    #pragma unroll
    for (int ni = 0; ni < 4; ++ni)
      #pragma unroll
      for (int r = 0; r < 4; ++r)
        C[(size_t)(crow0 + mi * 16 + r) * DM + (ccol0 + ni * 16)] = acc[mi][ni][r];
}

// One wave per query i, all 16 heads at once. Lane L owns dims [16L, 16L+16)
// of the 1024-dim row (head = L>>2). K/V row loads are fully coalesced (2KB/wave).
// Attended set = {i} U {i-2^t : t>=0, i-2^t>=0} (include_local=2 merges with powers).
__global__ __launch_bounds__(256)
void dilated_attn(const bf16_t* __restrict__ Q, const bf16_t* __restrict__ K,
                  const bf16_t* __restrict__ V, bf16_t* O)
{
  const int lane = threadIdx.x & 63;
  const int i = blockIdx.x * 4 + (threadIdx.x >> 6);
  const size_t base = (size_t)i * DM + lane * 16;

  bf16x8 q0 = *(const bf16x8*)(Q + base);
  bf16x8 q1 = *(const bf16x8*)(Q + base + 8);
  float qf[16];
  #pragma unroll
  for (int j = 0; j < 8; ++j) { qf[j] = (float)q0[j] * 0.125f; qf[j + 8] = (float)q1[j] * 0.125f; }

  float m = -INFINITY, l = 0.0f;
  float acc[16];
  #pragma unroll
  for (int j = 0; j < 16; ++j) acc[j] = 0.0f;

  int off = 1;
  size_t rb = base;
  bf16x8 k0 = *(const bf16x8*)(K + rb), k1 = *(const bf16x8*)(K + rb + 8);
  bf16x8 v0 = *(const bf16x8*)(V + rb), v1 = *(const bf16x8*)(V + rb + 8);

  while (true) {
    const int pn = i - off;
    const bool more = (pn >= 0);           // wave-uniform
    bf16x8 nk0, nk1, nv0, nv1;
    if (more) {                            // prefetch next position
      size_t nb = (size_t)pn * DM + lane * 16;
      nk0 = *(const bf16x8*)(K + nb); nk1 = *(const bf16x8*)(K + nb + 8);
      nv0 = *(const bf16x8*)(V + nb); nv1 = *(const bf16x8*)(V + nb + 8);
    }

    float sc = 0.0f;
    #pragma unroll
    for (int j = 0; j < 8; ++j) sc += qf[j] * (float)k0[j] + qf[j + 8] * (float)k1[j];
    sc += __shfl_xor(sc, 1, 64);           // sum across the 4 lanes of this head
    sc += __shfl_xor(sc, 2, 64);

    float mn = fmaxf(m, sc);
    float co = __expf(m - mn);
    float w  = __expf(sc - mn);
    l = l * co + w;
    m = mn;
    #pragma unroll
    for (int j = 0; j < 8; ++j) {
      acc[j]     = acc[j]     * co + w * (float)v0[j];
      acc[j + 8] = acc[j + 8] * co + w * (float)v1[j];
    }

    if (!more) break;
    k0 = nk0; k1 = nk1; v0 = nv0; v1 = nv1;
    off <<= 1;
  }

  const float inv = 1.0f / l;
  bf16x8 o0, o1;
  #pragma unroll
  for (int j = 0; j < 8; ++j) { o0[j] = (bf16_t)(acc[j] * inv); o1[j] = (bf16_t)(acc[j + 8] * inv); }
  *(bf16x8*)(O + base)     = o0;
  *(bf16x8*)(O + base + 8) = o1;
}

extern "C" void kernel_launch(void* const* d_in, const int* in_sizes, int n_in,
                              void* d_out, int out_size, void* d_ws, size_t ws_size,
                              hipStream_t stream) {
  (void)in_sizes; (void)n_in; (void)out_size; (void)ws_size;
  const float* x  = (const float*)d_in[0];
  const float* qw = (const float*)d_in[1];
  const float* kw = (const float*)d_in[2];
  const float* vw = (const float*)d_in[3];
  const float* ow = (const float*)d_in[4];
  // d_in[5] (positions) and d_in[6] (attend_mask) recomputed analytically in-kernel
  float* out = (float*)d_out;

  bf16_t* Xb  = (bf16_t*)d_ws;                       // 8192x1024
  bf16_t* Qb  = Xb  + (size_t)SEQ * DM;
  bf16_t* Kb  = Qb  + (size_t)SEQ * DM;
  bf16_t* Vb  = Kb  + (size_t)SEQ * DM;
  bf16_t* QWb = Vb  + (size_t)SEQ * DM;              // 1024x1024 x4
  bf16_t* KWb = QWb + (size_t)DM * DM;
  bf16_t* VWb = KWb + (size_t)DM * DM;
  bf16_t* OWb = VWb + (size_t)DM * DM;
  bf16_t* AO  = Qb;  // alias Q: each attn wave reads its own q row before writing it

  cvt_all<<<dim3(8192 + 4096), dim3(256), 0, stream>>>(x, qw, kw, vw, ow,
                                                       Xb, QWb, KWb, VWb, OWb);

  dim3 block(256);
  gemm_qkv_fused<<<dim3(SEQ / 128, DM / 64), block, 0, stream>>>(Xb, QWb, KWb, VWb, Qb, Kb, Vb);
  dilated_attn<<<dim3(SEQ / 4), block, 0, stream>>>(Qb, Kb, Vb, AO);
  gemm_out<<<dim3(SEQ / 128, DM / 128), block, 0, stream>>>(AO, OWb, out);
}

// Round 5
// 226.909 us; speedup vs baseline: 1.0210x; 1.0210x over previous
//
#include <hip/hip_runtime.h>
#include <hip/hip_bf16.h>

typedef __bf16 bf16_t;
typedef __bf16 bf16x4 __attribute__((ext_vector_type(4)));
typedef __bf16 bf16x8 __attribute__((ext_vector_type(8)));
typedef float floatx4 __attribute__((ext_vector_type(4)));

#define SEQ    8192
#define DM     1024
#define NHEADS 16
#define HDIM   64

// async global->LDS, 16B per lane; LDS dest is wave-uniform base + lane*16
__device__ __forceinline__ void async_ld16(bf16_t* lds, const bf16_t* g) {
  __builtin_amdgcn_global_load_lds(
      (__attribute__((address_space(1))) void*)g,
      (__attribute__((address_space(3))) void*)lds, 16, 0, 0);
}

// one launch converts x (8192 blocks) + 4 weight matrices (1024 blocks each)
__global__ __launch_bounds__(256)
void cvt_all(const float* __restrict__ x,  const float* __restrict__ qw,
             const float* __restrict__ kw, const float* __restrict__ vw,
             const float* __restrict__ ow,
             bf16_t* __restrict__ Xb,  bf16_t* __restrict__ QWb,
             bf16_t* __restrict__ KWb, bf16_t* __restrict__ VWb,
             bf16_t* __restrict__ OWb) {
  const int b = blockIdx.x;
  const float* in; bf16_t* out; int g;
  if (b < 8192) { in = x; out = Xb; g = b; }
  else {
    const int w  = (b - 8192) >> 10;
    const int wb = (b - 8192) & 1023;
    switch (w) {
      case 0:  in = qw; out = QWb; break;
      case 1:  in = kw; out = KWb; break;
      case 2:  in = vw; out = VWb; break;
      default: in = ow; out = OWb; break;
    }
    g = wb;
  }
  const int idx = (g * 256 + threadIdx.x) * 4;
  float4 v = *(const float4*)(in + idx);
  bf16x4 o = { (bf16_t)v.x, (bf16_t)v.y, (bf16_t)v.z, (bf16_t)v.w };
  *(bf16x4*)(out + idx) = o;
}

// C[m][n] = sum_k A[m][k]*B[n][k]; A 8192x1024, B 1024x1024, row-major bf16 in, OutT out.
// 128x128 tile, BK=32, 4 waves (2x2 of 64x64), 16 MFMA 16x16x32 per K-step.
// (m97 structure; round-4's in-block QKV fusion regressed via VGPR/occupancy -- reverted)
template <typename OutT>
__device__ __forceinline__ void gemm_body(const bf16_t* __restrict__ A,
                                          const bf16_t* __restrict__ B,
                                          OutT* __restrict__ C,
                                          int bx, int by)
{
  constexpr int Kdim = DM;
  __shared__ __attribute__((aligned(16))) bf16_t sA[128 * 32];
  __shared__ __attribute__((aligned(16))) bf16_t sB[128 * 32];

  const int tid  = threadIdx.x;
  const int wave = tid >> 6;
  const int lane = tid & 63;
  const int quad = lane >> 4;
  const int r16  = lane & 15;
  const int wr   = (wave >> 1) * 64;
  const int wc   = (wave & 1) * 64;

  const size_t arow0 = (size_t)bx * 128 + wave * 32 + (lane >> 2);
  const size_t brow0 = (size_t)by * 128 + wave * 32 + (lane >> 2);
  const bf16_t* Ag = A + arow0 * Kdim + (lane & 3) * 8;
  const bf16_t* Bg = B + brow0 * Kdim + (lane & 3) * 8;
  bf16_t* sAw = sA + wave * 32 * 32;
  bf16_t* sBw = sB + wave * 32 * 32;

  floatx4 acc[4][4];
  #pragma unroll
  for (int i = 0; i < 4; ++i)
    #pragma unroll
    for (int j = 0; j < 4; ++j)
      acc[i][j] = (floatx4)(0.0f);

  for (int ko = 0; ko < Kdim; ko += 32) {
    async_ld16(sAw,           Ag + ko);
    async_ld16(sAw + 16 * 32, Ag + 16 * Kdim + ko);
    async_ld16(sBw,           Bg + ko);
    async_ld16(sBw + 16 * 32, Bg + 16 * Kdim + ko);
    __syncthreads();

    bf16x8 af[4], bfr[4];
    #pragma unroll
    for (int mi = 0; mi < 4; ++mi)
      af[mi] = *(const bf16x8*)&sA[(wr + mi * 16 + r16) * 32 + quad * 8];
    #pragma unroll
    for (int ni = 0; ni < 4; ++ni)
      bfr[ni] = *(const bf16x8*)&sB[(wc + ni * 16 + r16) * 32 + quad * 8];

    #pragma unroll
    for (int mi = 0; mi < 4; ++mi)
      #pragma unroll
      for (int ni = 0; ni < 4; ++ni)
        acc[mi][ni] = __builtin_amdgcn_mfma_f32_16x16x32_bf16(af[mi], bfr[ni], acc[mi][ni], 0, 0, 0);

    __syncthreads();
  }

  // C/D layout: col = lane&15, row = (lane>>4)*4 + reg  [measured m89/m91]
  const int crow0 = bx * 128 + wr + quad * 4;
  const int ccol0 = by * 128 + wc + r16;
  #pragma unroll
  for (int mi = 0; mi < 4; ++mi)
    #pragma unroll
    for (int ni = 0; ni < 4; ++ni)
      #pragma unroll
      for (int r = 0; r < 4; ++r)
        C[(size_t)(crow0 + mi * 16 + r) * DM + (ccol0 + ni * 16)] = (OutT)acc[mi][ni][r];
}

// fused Q/K/V projections: blockIdx.z selects the weight/output pair
__global__ __launch_bounds__(256)
void gemm_qkv(const bf16_t* __restrict__ A,
              const bf16_t* __restrict__ Bq, const bf16_t* __restrict__ Bk,
              const bf16_t* __restrict__ Bv,
              bf16_t* __restrict__ Cq, bf16_t* __restrict__ Ck, bf16_t* __restrict__ Cv)
{
  const bf16_t* B = (blockIdx.z == 0) ? Bq : (blockIdx.z == 1) ? Bk : Bv;
  bf16_t*       C = (blockIdx.z == 0) ? Cq : (blockIdx.z == 1) ? Ck : Cv;
  gemm_body<bf16_t>(A, B, C, blockIdx.x, blockIdx.y);
}

__global__ __launch_bounds__(256)
void gemm_out(const bf16_t* __restrict__ A, const bf16_t* __restrict__ B,
              float* __restrict__ C)
{
  gemm_body<float>(A, B, C, blockIdx.x, blockIdx.y);
}

// One wave per query i, all 16 heads at once. Lane L owns dims [16L, 16L+16)
// of the 1024-dim row (head = L>>2). K/V row loads are fully coalesced (2KB/wave).
// Attended set = {i} U {i-2^t : t>=0, i-2^t>=0}.
// XCD-affinity swizzle: congruence class blockIdx.x%8 (-> one XCD under round-robin
// dispatch) covers a contiguous 1024-query region, so near-offset K/V rows
// (off<=512, ~10 of 14 positions) stay in that XCD's 4MB L2 (2MB K + 2MB V region).
__global__ __launch_bounds__(256)
void dilated_attn(const bf16_t* __restrict__ Q, const bf16_t* __restrict__ K,
                  const bf16_t* __restrict__ V, bf16_t* O)
{
  const int lane = threadIdx.x & 63;
  const int qb   = (blockIdx.x & 7) * 256 + (blockIdx.x >> 3);  // XCD swizzle
  const int i    = qb * 4 + (threadIdx.x >> 6);
  const size_t base = (size_t)i * DM + lane * 16;

  bf16x8 q0 = *(const bf16x8*)(Q + base);
  bf16x8 q1 = *(const bf16x8*)(Q + base + 8);
  float qf[16];
  #pragma unroll
  for (int j = 0; j < 8; ++j) { qf[j] = (float)q0[j] * 0.125f; qf[j + 8] = (float)q1[j] * 0.125f; }

  float m = -INFINITY, l = 0.0f;
  float acc[16];
  #pragma unroll
  for (int j = 0; j < 16; ++j) acc[j] = 0.0f;

  int off = 1;
  bf16x8 k0 = *(const bf16x8*)(K + base), k1 = *(const bf16x8*)(K + base + 8);
  bf16x8 v0 = *(const bf16x8*)(V + base), v1 = *(const bf16x8*)(V + base + 8);

  while (true) {
    const int pn = i - off;
    const bool more = (pn >= 0);           // wave-uniform
    bf16x8 nk0, nk1, nv0, nv1;
    if (more) {                            // prefetch next position
      size_t nb = (size_t)pn * DM + lane * 16;
      nk0 = *(const bf16x8*)(K + nb); nk1 = *(const bf16x8*)(K + nb + 8);
      nv0 = *(const bf16x8*)(V + nb); nv1 = *(const bf16x8*)(V + nb + 8);
    }

    float sc = 0.0f;
    #pragma unroll
    for (int j = 0; j < 8; ++j) sc += qf[j] * (float)k0[j] + qf[j + 8] * (float)k1[j];
    sc += __shfl_xor(sc, 1, 64);           // sum across the 4 lanes of this head
    sc += __shfl_xor(sc, 2, 64);

    float mn = fmaxf(m, sc);
    float co = __expf(m - mn);
    float w  = __expf(sc - mn);
    l = l * co + w;
    m = mn;
    #pragma unroll
    for (int j = 0; j < 8; ++j) {
      acc[j]     = acc[j]     * co + w * (float)v0[j];
      acc[j + 8] = acc[j + 8] * co + w * (float)v1[j];
    }

    if (!more) break;
    k0 = nk0; k1 = nk1; v0 = nv0; v1 = nv1;
    off <<= 1;
  }

  const float inv = 1.0f / l;
  bf16x8 o0, o1;
  #pragma unroll
  for (int j = 0; j < 8; ++j) { o0[j] = (bf16_t)(acc[j] * inv); o1[j] = (bf16_t)(acc[j + 8] * inv); }
  *(bf16x8*)(O + base)     = o0;
  *(bf16x8*)(O + base + 8) = o1;
}

extern "C" void kernel_launch(void* const* d_in, const int* in_sizes, int n_in,
                              void* d_out, int out_size, void* d_ws, size_t ws_size,
                              hipStream_t stream) {
  (void)in_sizes; (void)n_in; (void)out_size; (void)ws_size;
  const float* x  = (const float*)d_in[0];
  const float* qw = (const float*)d_in[1];
  const float* kw = (const float*)d_in[2];
  const float* vw = (const float*)d_in[3];
  const float* ow = (const float*)d_in[4];
  // d_in[5] (positions) and d_in[6] (attend_mask) recomputed analytically in-kernel
  float* out = (float*)d_out;

  bf16_t* Xb  = (bf16_t*)d_ws;                       // 8192x1024
  bf16_t* Qb  = Xb  + (size_t)SEQ * DM;
  bf16_t* Kb  = Qb  + (size_t)SEQ * DM;
  bf16_t* Vb  = Kb  + (size_t)SEQ * DM;
  bf16_t* QWb = Vb  + (size_t)SEQ * DM;              // 1024x1024 x4
  bf16_t* KWb = QWb + (size_t)DM * DM;
  bf16_t* VWb = KWb + (size_t)DM * DM;
  bf16_t* OWb = VWb + (size_t)DM * DM;
  bf16_t* AO  = Qb;  // alias Q: each attn wave reads its own q row before writing it

  cvt_all<<<dim3(8192 + 4096), dim3(256), 0, stream>>>(x, qw, kw, vw, ow,
                                                       Xb, QWb, KWb, VWb, OWb);

  dim3 block(256);
  gemm_qkv<<<dim3(SEQ / 128, DM / 128, 3), block, 0, stream>>>(Xb, QWb, KWb, VWb, Qb, Kb, Vb);
  dilated_attn<<<dim3(SEQ / 4), block, 0, stream>>>(Qb, Kb, Vb, AO);
  gemm_out<<<dim3(SEQ / 128, DM / 128), block, 0, stream>>>(AO, OWb, out);
}